// Round 4
// baseline (299.999 us; speedup 1.0000x reference)
//
#include <hip/hip_runtime.h>
#include <hip/hip_bf16.h>

#define B_ 8
#define N_ 256
#define H_ 128
#define E_ 32
#define XS_STRIDE 132   // 128 + 4: epilogue ds_read bank aliasing <= 2-way (free)

typedef __bf16 bf16x8 __attribute__((ext_vector_type(8)));
typedef float f32x4 __attribute__((ext_vector_type(4)));

// round-to-nearest-even fp32 -> bf16
static __device__ __forceinline__ __bf16 f2bf(float f) {
    union { float f; unsigned int u; } a;
    a.f = f;
    const unsigned int r = a.u + 0x7FFFu + ((a.u >> 16) & 1u);
    union { unsigned short s; __bf16 b; } o;
    o.s = (unsigned short)(r >> 16);
    return o.b;
}

// Fused kernel, 4 graph-nodes i per WG (grid 512, 256 thr, 2 blocks/CU).
//   h[i,:] = x[b,i,:] + sum_j adj[b,i,j]*relu(x[b,j,:] + e[b,i,j,:]@We + be)
//   out[i,:] = relu(h@W1+b1)@W2 + b2
// Why 4 i/WG (round-3 was 1 i/WG, latency-bound at 78us, all pipes <25%):
//  - We fragments (72 scalar loads) amortized 4x
//  - MLP W1/W2 reads amortized 4x (L2 traffic 512 MB -> 128 MB)
//  - x epilogue rows staged in LDS once per j-chunk (coalesced float4),
//    reused by the i-pair -> 128 scalar loads/i -> 64 dwordx4 total
// Phase 1 runs 2 passes of an i-pair so psum[2][8]=16 regs (not 32);
// __launch_bounds__(256,2): gfx950 splits budget 50/50 arch/AGPR -> 128 arch.
__global__ __launch_bounds__(256, 2) void fused_kernel(
    const float* __restrict__ x, const int* __restrict__ adj,
    const float* __restrict__ e, const float* __restrict__ We,
    const float* __restrict__ be, const float* __restrict__ W1,
    const float* __restrict__ b1, const float* __restrict__ W2,
    const float* __restrict__ b2, float* __restrict__ out)
{
    __shared__ float xs[4][16 * XS_STRIDE];  // per-wave x-row staging (no barrier)
    __shared__ float red[4][2][128];
    __shared__ float hvec[4][128];
    __shared__ float ts[4][256];
    __shared__ float part[4][256];

    const int tile = blockIdx.x;            // 512 tiles of 4 i
    const int b    = tile >> 6;
    const int i0   = (tile & 63) << 2;
    const int tid  = threadIdx.x;
    const int w    = tid >> 6;
    const int lane = tid & 63;
    const int quad = lane >> 4;
    const int col  = lane & 15;

    // Preload all of We as B-fragments (8 h-tiles x 8 bf16 = 32 VGPRs) + be.
    bf16x8 bw[8];
    float  bef[8];
#pragma unroll
    for (int ht = 0; ht < 8; ++ht) {
#pragma unroll
        for (int kk = 0; kk < 8; ++kk)
            bw[ht][kk] = f2bf(We[(quad * 8 + kk) * H_ + ht * 16 + col]);
        bef[ht] = be[ht * 16 + col];
    }

    const f32x4 zero4 = {0.0f, 0.0f, 0.0f, 0.0f};

    for (int pass = 0; pass < 2; ++pass) {
        const int ia = i0 + pass * 2;

        float psum[2][8];
#pragma unroll
        for (int ii = 0; ii < 2; ++ii)
#pragma unroll
            for (int ht = 0; ht < 8; ++ht) psum[ii][ht] = 0.0f;

#pragma unroll
        for (int c = 0; c < 4; ++c) {
            const int j0 = (c * 4 + w) * 16;

            // Stage x[b, j0..j0+15, :] into this wave's LDS region (coalesced
            // float4; row stride 132 so epilogue scalar reads are <=2-way).
            {
                const float* src = x + ((size_t)(b * N_ + j0)) * H_;
#pragma unroll
                for (int q = 0; q < 8; ++q) {
                    const int idx = q * 64 + lane;          // float4 index
                    const int row = idx >> 5, c4 = idx & 31;
                    const float4 v = *(const float4*)(src + (size_t)idx * 4);
                    *(float4*)&xs[w][row * XS_STRIDE + c4 * 4] = v;
                }
            }

            const int jr = j0 + quad * 4;

#pragma unroll
            for (int ii = 0; ii < 2; ++ii) {
                const int i = ia + ii;
                const size_t rowbase = (size_t)(b * N_ + i) * N_;

                // adj mask, one int4 for this lane's 4 j-rows.
                const int4 av = *(const int4*)(adj + rowbase + jr);
                float adjf[4];
                adjf[0] = av.x ? 1.0f : 0.0f;
                adjf[1] = av.y ? 1.0f : 0.0f;
                adjf[2] = av.z ? 1.0f : 0.0f;
                adjf[3] = av.w ? 1.0f : 0.0f;

                // A fragment: e[b,i, j0+col, quad*8 .. +7]
                const float* ap = e + (rowbase + (size_t)(j0 + col)) * E_ + quad * 8;
                const float4 a0 = *(const float4*)ap;
                const float4 a1 = *(const float4*)(ap + 4);
                bf16x8 af;
                af[0] = f2bf(a0.x); af[1] = f2bf(a0.y); af[2] = f2bf(a0.z); af[3] = f2bf(a0.w);
                af[4] = f2bf(a1.x); af[5] = f2bf(a1.y); af[6] = f2bf(a1.z); af[7] = f2bf(a1.w);

                // Two groups of 4 h-tiles (16 acc regs live per group).
#pragma unroll
                for (int g = 0; g < 2; ++g) {
                    f32x4 acc[4];
#pragma unroll
                    for (int t = 0; t < 4; ++t)
                        acc[t] = __builtin_amdgcn_mfma_f32_16x16x32_bf16(af, bw[g * 4 + t], zero4, 0, 0, 0);
#pragma unroll
                    for (int r = 0; r < 4; ++r) {
                        const float* xr = &xs[w][(quad * 4 + r) * XS_STRIDE + col];
#pragma unroll
                        for (int t = 0; t < 4; ++t) {
                            const int ht = g * 4 + t;
                            const float v = acc[t][r] + xr[ht * 16] + bef[ht];
                            psum[ii][ht] += adjf[r] * fmaxf(v, 0.0f);
                        }
                    }
                }
            }
        }

        // Quad reduce in-register, wave reduce via LDS; h = agg + x[b,i,:].
#pragma unroll
        for (int ii = 0; ii < 2; ++ii)
#pragma unroll
            for (int ht = 0; ht < 8; ++ht) {
                float v = psum[ii][ht];
                v += __shfl_xor(v, 16);
                v += __shfl_xor(v, 32);
                if (lane < 16) red[w][ii][ht * 16 + lane] = v;
            }
        __syncthreads();
        {
            const int g = tid >> 7, t = tid & 127;
            const float aggv = red[0][g][t] + red[1][g][t] + red[2][g][t] + red[3][g][t];
            hvec[pass * 2 + g][t] = aggv + x[((size_t)(b * N_ + ia + g)) * H_ + t];
        }
        __syncthreads();   // red reused next pass; hvec complete for MLP
    }

    // ---- MLP (fp32). Weights from L2 (384 KB, shared by all WGs), 4 rows
    // share every W load.
    // Layer 1: thread owns output column c = tid for all 4 rows.
    {
        const int c = tid;
        float acc[4] = {0.f, 0.f, 0.f, 0.f};
        for (int k = 0; k < 128; k += 4) {
            const float w0 = W1[(k + 0) * 256 + c];
            const float w1 = W1[(k + 1) * 256 + c];
            const float w2 = W1[(k + 2) * 256 + c];
            const float w3 = W1[(k + 3) * 256 + c];
#pragma unroll
            for (int r = 0; r < 4; ++r) {
                const float4 hv = *(const float4*)&hvec[r][k];   // ds_read_b128
                acc[r] += hv.x * w0 + hv.y * w1 + hv.z * w2 + hv.w * w3;
            }
        }
        const float bb = b1[c];
#pragma unroll
        for (int r = 0; r < 4; ++r) ts[r][c] = fmaxf(acc[r] + bb, 0.0f);
    }
    __syncthreads();

    // Layer 2: two threads per column (k split 128/128), 4 rows each.
    {
        const int cc = tid & 127;
        const int kb = (tid >> 7) * 128;
        float acc[4] = {0.f, 0.f, 0.f, 0.f};
        for (int k = 0; k < 128; k += 4) {
            const float w0 = W2[(kb + k + 0) * 128 + cc];
            const float w1 = W2[(kb + k + 1) * 128 + cc];
            const float w2 = W2[(kb + k + 2) * 128 + cc];
            const float w3 = W2[(kb + k + 3) * 128 + cc];
#pragma unroll
            for (int r = 0; r < 4; ++r) {
                const float4 tv = *(const float4*)&ts[r][kb + k];
                acc[r] += tv.x * w0 + tv.y * w1 + tv.z * w2 + tv.w * w3;
            }
        }
#pragma unroll
        for (int r = 0; r < 4; ++r) part[r][tid] = acc[r];
    }
    __syncthreads();
    {
        const int t  = tid & 127;
        const int rb = (tid >> 7) * 2;
        const float bb = b2[t];
#pragma unroll
        for (int r2 = 0; r2 < 2; ++r2) {
            const int r = rb + r2;
            out[((size_t)(b * N_ + i0 + r)) * H_ + t] =
                part[r][t] + part[r][t + 128] + bb;
        }
    }
}

extern "C" void kernel_launch(void* const* d_in, const int* in_sizes, int n_in,
                              void* d_out, int out_size, void* d_ws, size_t ws_size,
                              hipStream_t stream) {
    const float* x   = (const float*)d_in[0];
    const int*   adj = (const int*)  d_in[1];
    const float* e   = (const float*)d_in[2];
    const float* We  = (const float*)d_in[3];
    const float* be  = (const float*)d_in[4];
    const float* W1  = (const float*)d_in[5];
    const float* b1  = (const float*)d_in[6];
    const float* W2  = (const float*)d_in[7];
    const float* b2  = (const float*)d_in[8];
    float* out = (float*)d_out;

    fused_kernel<<<dim3(B_ * N_ / 4), dim3(256), 0, stream>>>(
        x, adj, e, We, be, W1, b1, W2, b2, out);
}